// Round 5
// baseline (329.041 us; speedup 1.0000x reference)
//
#include <hip/hip_runtime.h>
#include <hip/hip_bf16.h>
#include <math.h>

#define M_TOT 8192
#define D_DIM 1024
#define E_NUM 8
#define P_DIM 1024
#define K_TOT (E_NUM * D_DIM)  // 8192
#define NT    (K_TOT / 64)     // 128 K-tiles

typedef __attribute__((ext_vector_type(8))) short short8;
typedef __attribute__((ext_vector_type(4))) float f32x4;
typedef __attribute__((ext_vector_type(8))) unsigned short u16x8;

// round-to-nearest-even f32 -> bf16 (finite inputs)
static __device__ __forceinline__ unsigned short f2bf(float f) {
  unsigned u = __builtin_bit_cast(unsigned, f);
  unsigned r = (u + 0x7fffu + ((u >> 16) & 1u)) >> 16;
  return (unsigned short)r;
}

// ---------------- gate: softmax(x @ gate_w + gate_b) -> [M, E] fp32 ----------------
__global__ __launch_bounds__(256) void gate_kernel(const float* __restrict__ x,
                                                   const float* __restrict__ gw,
                                                   const float* __restrict__ gb,
                                                   float* __restrict__ gate) {
  const int row  = blockIdx.x * 4 + (threadIdx.x >> 6);
  const int lane = threadIdx.x & 63;
  const float* xr = x + (size_t)row * D_DIM;
  float acc[E_NUM];
#pragma unroll
  for (int e = 0; e < E_NUM; ++e) acc[e] = 0.f;
#pragma unroll
  for (int it = 0; it < 16; ++it) {
    const int d = it * 64 + lane;
    const float xv = xr[d];
    const float4* g4 = reinterpret_cast<const float4*>(gw + (size_t)d * E_NUM);
    float4 a = g4[0], b = g4[1];
    acc[0] += xv * a.x; acc[1] += xv * a.y; acc[2] += xv * a.z; acc[3] += xv * a.w;
    acc[4] += xv * b.x; acc[5] += xv * b.y; acc[6] += xv * b.z; acc[7] += xv * b.w;
  }
#pragma unroll
  for (int off = 32; off >= 1; off >>= 1) {
#pragma unroll
    for (int e = 0; e < E_NUM; ++e) acc[e] += __shfl_xor(acc[e], off, 64);
  }
  if (lane == 0) {
    float v[E_NUM], mx = -1e30f;
#pragma unroll
    for (int e = 0; e < E_NUM; ++e) { v[e] = acc[e] + gb[e]; mx = fmaxf(mx, v[e]); }
    float s = 0.f;
#pragma unroll
    for (int e = 0; e < E_NUM; ++e) { v[e] = expf(v[e] - mx); s += v[e]; }
    const float inv = 1.f / s;
#pragma unroll
    for (int e = 0; e < E_NUM; ++e) gate[(size_t)row * E_NUM + e] = v[e] * inv;
  }
}

// ---------------- W [E][D][P] f32 -> wt [P][E*D] bf16, swizzle baked per 64-short K-block ----------------
__global__ __launch_bounds__(256) void wtrans2_kernel(const float* __restrict__ w,
                                                      unsigned short* __restrict__ wt) {
  __shared__ float tile[64][65];
  const int e  = blockIdx.z;
  const int p0 = blockIdx.y * 64;
  const int d0 = blockIdx.x * 64;
  const int tx = threadIdx.x & 63;
  const int ty = threadIdx.x >> 6;
  const float* src = w + ((size_t)e * D_DIM + d0) * P_DIM + p0;
#pragma unroll
  for (int i = 0; i < 16; ++i) {
    const int dr = i * 4 + ty;
    tile[dr][tx] = src[(size_t)dr * P_DIM + tx];
  }
  __syncthreads();
#pragma unroll
  for (int i = 0; i < 16; ++i) {
    const int pr = i * 4 + ty;
    const int c = tx ^ ((pr & 7) << 3);  // involution, 16B-chunk granular
    wt[(size_t)(p0 + pr) * K_TOT + e * D_DIM + d0 + c] = f2bf(tile[tx][pr]);
  }
}

// ---------------- A'[m][e*1024+d] = bf16(gate[m,e]*x[m,d]), swizzle baked per 64-short block ----------------
__global__ __launch_bounds__(256) void aprep_kernel(const float* __restrict__ x,
                                                    const float* __restrict__ gate,
                                                    unsigned short* __restrict__ ap) {
  const int tid = threadIdx.x;
  const int m   = blockIdx.x * 2 + (tid >> 7);
  const int jd  = tid & 127;
  const float4* xp = reinterpret_cast<const float4*>(x + (size_t)m * D_DIM + jd * 8);
  const float4 p = xp[0], q = xp[1];
  unsigned short* row = ap + (size_t)m * K_TOT;
  const int cbase = (jd >> 3) * 8 + ((jd & 7) ^ (m & 7));
#pragma unroll
  for (int e = 0; e < E_NUM; ++e) {
    const float gs = gate[(size_t)m * E_NUM + e];
    u16x8 v;
    v[0] = f2bf(p.x * gs); v[1] = f2bf(p.y * gs);
    v[2] = f2bf(p.z * gs); v[3] = f2bf(p.w * gs);
    v[4] = f2bf(q.x * gs); v[5] = f2bf(q.y * gs);
    v[6] = f2bf(q.z * gs); v[7] = f2bf(q.w * gs);
    *reinterpret_cast<u16x8*>(&row[(size_t)(e * 128 + cbase) * 8]) = v;
  }
}

// ---------------- triple-buffered counted-vmcnt GEMM: 128x256 tile, BK=64, 8 waves ----------------
static __device__ __forceinline__ short8 ldfrag(const unsigned short* buf, int row, int e0) {
  return *reinterpret_cast<const short8*>(&buf[row * 64 + (e0 ^ ((row & 7) << 3))]);
}

__global__ __launch_bounds__(512, 1) void gemm_tb_kernel(
    const unsigned short* __restrict__ ap,
    const unsigned short* __restrict__ wt,
    const float* __restrict__ gate,
    const float* __restrict__ eb,
    float* __restrict__ out) {
  __shared__ __align__(16) unsigned short lA[3 * 128 * 64];  // 48 KB
  __shared__ __align__(16) unsigned short lB[3 * 256 * 64];  // 96 KB
  __shared__ float lG[128 * 8];                              // 4 KB  -> 148 KB total

  const int tid  = threadIdx.x;
  const int lane = tid & 63;
  const int wid  = tid >> 6;
  const int wm   = wid >> 2;   // 0..1
  const int wn   = wid & 3;    // 0..3
  const int l15  = lane & 15;
  const int exb  = (lane >> 4) * 8;

  // XCD-aware bijective swizzle: 256 blocks; XCD pair shares one 256-wide n-panel
  // (4MB wt slice, L2-resident); consecutive idx -> consecutive m (A L2/L3 reuse).
  const int bid = blockIdx.x;
  const int xcd = bid & 7, idx = bid >> 3;
  const int m0  = ((xcd & 1) * 32 + idx) * 128;
  const int n0  = (xcd >> 1) * 256;

  if (tid < 256)
    reinterpret_cast<float4*>(lG)[tid] =
        reinterpret_cast<const float4*>(gate + (size_t)m0 * E_NUM)[tid];

  // staging: per thread row = tid>>3 (0..63), 16B chunk = tid&7; 6 rounds per tile
  const unsigned short* apRow = ap + (size_t)(m0 + (tid >> 3)) * K_TOT + (tid & 7) * 8;
  const unsigned short* wtRow = wt + (size_t)(n0 + (tid >> 3)) * K_TOT + (tid & 7) * 8;

  auto stage = [&](int t, unsigned short* bA, unsigned short* bB) {
    const int w = t & (NT - 1);  // wrap: tail stages re-read tile 0/1 into dead buffers
#pragma unroll
    for (int h = 0; h < 2; ++h)
      __builtin_amdgcn_global_load_lds(
          (const __attribute__((address_space(1))) void*)(apRow + (size_t)h * 64 * K_TOT + w * 64),
          (__attribute__((address_space(3))) void*)(bA + h * 4096 + tid * 8), 16, 0, 0);
#pragma unroll
    for (int r = 0; r < 4; ++r)
      __builtin_amdgcn_global_load_lds(
          (const __attribute__((address_space(1))) void*)(wtRow + (size_t)r * 64 * K_TOT + w * 64),
          (__attribute__((address_space(3))) void*)(bB + r * 4096 + tid * 8), 16, 0, 0);
  };

  f32x4 acc[4][4];
#pragma unroll
  for (int i = 0; i < 4; ++i)
#pragma unroll
    for (int j = 0; j < 4; ++j)
#pragma unroll
      for (int k = 0; k < 4; ++k) acc[i][j][k] = 0.f;

  // prologue: tiles 0,1 -> bufs 0,1 (12 loads); retire tile0's 6; barrier
  stage(0, lA, lB);
  stage(1, lA + 8192, lB + 16384);
  asm volatile("s_waitcnt vmcnt(6)" ::: "memory");
  __builtin_amdgcn_s_barrier();
  asm volatile("" ::: "memory");

  int cur = 0, sb = 2;
#pragma unroll 1
  for (int t = 0; t < NT; ++t) {
    const unsigned short* bufA = lA + cur * 8192;
    const unsigned short* bufB = lB + cur * 16384;

    // issue next-next tile's staging first (lands before vmcnt at end of t+1)
    stage(t + 2, lA + sb * 8192, lB + sb * 16384);

    // 4 quadrant phases, no mid-tile barriers (all waves read-only buf cur)
#pragma unroll
    for (int mh = 0; mh < 2; ++mh) {
#pragma unroll
      for (int nh = 0; nh < 2; ++nh) {
        const int ra0 = wm * 64 + mh * 32 + l15, ra1 = ra0 + 16;
        const int rb0 = wn * 64 + nh * 32 + l15, rb1 = rb0 + 16;
        short8 a00 = ldfrag(bufA, ra0, exb),      a10 = ldfrag(bufA, ra1, exb);
        short8 b00 = ldfrag(bufB, rb0, exb),      b10 = ldfrag(bufB, rb1, exb);
        short8 a01 = ldfrag(bufA, ra0, 32 + exb), a11 = ldfrag(bufA, ra1, 32 + exb);
        short8 b01 = ldfrag(bufB, rb0, 32 + exb), b11 = ldfrag(bufB, rb1, 32 + exb);
        f32x4* am0 = &acc[mh * 2][nh * 2];
        f32x4* am1 = &acc[mh * 2 + 1][nh * 2];
        __builtin_amdgcn_s_setprio(1);
        am0[0] = __builtin_amdgcn_mfma_f32_16x16x32_bf16(a00, b00, am0[0], 0, 0, 0);
        am0[1] = __builtin_amdgcn_mfma_f32_16x16x32_bf16(a00, b10, am0[1], 0, 0, 0);
        am1[0] = __builtin_amdgcn_mfma_f32_16x16x32_bf16(a10, b00, am1[0], 0, 0, 0);
        am1[1] = __builtin_amdgcn_mfma_f32_16x16x32_bf16(a10, b10, am1[1], 0, 0, 0);
        am0[0] = __builtin_amdgcn_mfma_f32_16x16x32_bf16(a01, b01, am0[0], 0, 0, 0);
        am0[1] = __builtin_amdgcn_mfma_f32_16x16x32_bf16(a01, b11, am0[1], 0, 0, 0);
        am1[0] = __builtin_amdgcn_mfma_f32_16x16x32_bf16(a11, b01, am1[0], 0, 0, 0);
        am1[1] = __builtin_amdgcn_mfma_f32_16x16x32_bf16(a11, b11, am1[1], 0, 0, 0);
        __builtin_amdgcn_s_setprio(0);
      }
    }

    // retire tile t+1's 6 loads (12 outstanding -> 6), publish to all waves
    asm volatile("s_waitcnt vmcnt(6)" ::: "memory");
    __builtin_amdgcn_s_barrier();
    asm volatile("" ::: "memory");

    cur = (cur == 2) ? 0 : cur + 1;
    sb  = (sb == 2) ? 0 : sb + 1;
  }

  // ---- epilogue: gate-weighted bias (eb direct from L2) + store ----
#pragma unroll
  for (int n = 0; n < 4; ++n) {
    const int cl = wn * 64 + n * 16 + l15;
    float lb[E_NUM];
#pragma unroll
    for (int e = 0; e < E_NUM; ++e) lb[e] = eb[(size_t)e * P_DIM + n0 + cl];
#pragma unroll
    for (int m = 0; m < 4; ++m) {
#pragma unroll
      for (int reg = 0; reg < 4; ++reg) {
        const int r = wm * 64 + m * 16 + (lane >> 4) * 4 + reg;
        float bs = 0.f;
#pragma unroll
        for (int e = 0; e < E_NUM; ++e) bs += lG[r * 8 + e] * lb[e];
        out[(size_t)(m0 + r) * P_DIM + n0 + cl] = acc[m][n][reg] + bs;
      }
    }
  }
}

// ============================ FALLBACK PATH (round-2, passing) ============================

__global__ __launch_bounds__(256) void wtrans_kernel(const float* __restrict__ w,
                                                     unsigned short* __restrict__ wt) {
  __shared__ float tile[64][65];
  const int e  = blockIdx.z;
  const int p0 = blockIdx.y * 64;
  const int d0 = blockIdx.x * 64;
  const int tx = threadIdx.x & 63;
  const int ty = threadIdx.x >> 6;
  const float* src = w + ((size_t)e * D_DIM + d0) * P_DIM + p0;
#pragma unroll
  for (int i = 0; i < 16; ++i) {
    const int dr = i * 4 + ty;
    tile[dr][tx] = src[(size_t)dr * P_DIM + tx];
  }
  __syncthreads();
  unsigned short* dst = wt + ((size_t)e * P_DIM + p0) * D_DIM + d0;
#pragma unroll
  for (int i = 0; i < 16; ++i) {
    const int pr = i * 4 + ty;
    const int c = tx ^ ((pr & 7) << 3);
    dst[(size_t)pr * D_DIM + c] = f2bf(tile[tx][pr]);
  }
}

__global__ __launch_bounds__(256, 2) void moe_gemm_kernel(
    const float* __restrict__ x,
    const unsigned short* __restrict__ wt,
    const float* __restrict__ gate,
    const float* __restrict__ eb,
    float* __restrict__ out) {
  __shared__ unsigned short lA[128 * 64];
  __shared__ unsigned short lB[128 * 64];
  __shared__ float lG[128 * 8];
  __shared__ float lBias[E_NUM * 128];

  const int tid  = threadIdx.x;
  const int lane = tid & 63;
  const int wid  = tid >> 6;
  const int wr   = wid >> 1, wc = wid & 1;
  const int m0   = blockIdx.x * 128;
  const int n0   = blockIdx.y * 128;

  reinterpret_cast<float4*>(lG)[tid] =
      reinterpret_cast<const float4*>(gate + (size_t)m0 * E_NUM)[tid];
  {
    const int e = tid >> 5, c = (tid & 31) * 4;
    *reinterpret_cast<float4*>(&lBias[e * 128 + c]) =
        *reinterpret_cast<const float4*>(&eb[(size_t)e * P_DIM + n0 + c]);
  }
  __syncthreads();

  const int rA   = tid >> 1;
  const int colA = (tid & 1) * 32;
  const float* xrow = x + (size_t)(m0 + rA) * D_DIM + colA;

  f32x4 acc[4][4];
#pragma unroll
  for (int i = 0; i < 4; ++i)
#pragma unroll
    for (int j = 0; j < 4; ++j)
#pragma unroll
      for (int k = 0; k < 4; ++k) acc[i][j][k] = 0.f;

  for (int e = 0; e < E_NUM; ++e) {
    const float gs = lG[rA * 8 + e];
    const unsigned short* wte = wt + ((size_t)e * P_DIM + n0) * D_DIM;
    for (int kt = 0; kt < 16; ++kt) {
      __syncthreads();
      const float4* apv = reinterpret_cast<const float4*>(xrow + kt * 64);
#pragma unroll
      for (int j = 0; j < 4; ++j) {
        float4 p = apv[2 * j], q = apv[2 * j + 1];
        u16x8 v;
        v[0] = f2bf(p.x * gs); v[1] = f2bf(p.y * gs);
        v[2] = f2bf(p.z * gs); v[3] = f2bf(p.w * gs);
        v[4] = f2bf(q.x * gs); v[5] = f2bf(q.y * gs);
        v[6] = f2bf(q.z * gs); v[7] = f2bf(q.w * gs);
        const int idx = rA * 64 + ((colA + j * 8) ^ ((rA & 7) << 3));
        *reinterpret_cast<u16x8*>(&lA[idx]) = v;
      }
#pragma unroll
      for (int i = 0; i < 4; ++i) {
        const int u  = tid + i * 256;
        const int rr = u >> 3;
        const int cc = u & 7;
        const unsigned short* src = wte + (size_t)rr * D_DIM + kt * 64 + cc * 8;
        __builtin_amdgcn_global_load_lds(
            (const __attribute__((address_space(1))) void*)src,
            (__attribute__((address_space(3))) void*)&lB[u * 8], 16, 0, 0);
      }
      __syncthreads();
#pragma unroll
      for (int kk = 0; kk < 2; ++kk) {
        const int e0 = kk * 32 + (lane >> 4) * 8;
        short8 a[4], b[4];
#pragma unroll
        for (int m = 0; m < 4; ++m) {
          const int r = wr * 64 + m * 16 + (lane & 15);
          a[m] = *reinterpret_cast<const short8*>(&lA[r * 64 + (e0 ^ ((r & 7) << 3))]);
        }
#pragma unroll
        for (int n = 0; n < 4; ++n) {
          const int r = wc * 64 + n * 16 + (lane & 15);
          b[n] = *reinterpret_cast<const short8*>(&lB[r * 64 + (e0 ^ ((r & 7) << 3))]);
        }
#pragma unroll
        for (int m = 0; m < 4; ++m)
#pragma unroll
          for (int n = 0; n < 4; ++n)
            acc[m][n] = __builtin_amdgcn_mfma_f32_16x16x32_bf16(a[m], b[n], acc[m][n], 0, 0, 0);
      }
    }
  }

#pragma unroll
  for (int m = 0; m < 4; ++m) {
#pragma unroll
    for (int n = 0; n < 4; ++n) {
      const int rbase = wr * 64 + m * 16 + ((lane >> 4) * 4);
      const int cl    = wc * 64 + n * 16 + (lane & 15);
#pragma unroll
      for (int reg = 0; reg < 4; ++reg) {
        const int r = rbase + reg;
        float bsum = 0.f;
#pragma unroll
        for (int e = 0; e < E_NUM; ++e) bsum += lG[r * 8 + e] * lBias[e * 128 + cl];
        out[(size_t)(m0 + r) * P_DIM + n0 + cl] = acc[m][n][reg] + bsum;
      }
    }
  }
}

// ============================ launch ============================

extern "C" void kernel_launch(void* const* d_in, const int* in_sizes, int n_in,
                              void* d_out, int out_size, void* d_ws, size_t ws_size,
                              hipStream_t stream) {
  const float* x  = (const float*)d_in[0];
  const float* gw = (const float*)d_in[1];
  const float* gb = (const float*)d_in[2];
  const float* ew = (const float*)d_in[3];
  const float* eb = (const float*)d_in[4];
  float* out = (float*)d_out;

  char* ws = (char*)d_ws;
  float* gate        = (float*)ws;                     // 256 KiB
  unsigned short* wt = (unsigned short*)(ws + 262144); // 16 MiB

  const size_t need_big = 262144ull + 16777216ull + 134217728ull;

  gate_kernel<<<M_TOT / 4, 256, 0, stream>>>(x, gw, gb, gate);

  if (ws_size >= need_big) {
    unsigned short* apb = (unsigned short*)(ws + 262144 + 16777216);  // 128 MiB
    wtrans2_kernel<<<dim3(D_DIM / 64, P_DIM / 64, E_NUM), 256, 0, stream>>>(ew, wt);
    aprep_kernel<<<M_TOT / 2, 256, 0, stream>>>(x, gate, apb);
    gemm_tb_kernel<<<256, 512, 0, stream>>>(apb, wt, gate, eb, out);
  } else {
    wtrans_kernel<<<dim3(D_DIM / 64, P_DIM / 64, E_NUM), 256, 0, stream>>>(ew, wt);
    moe_gemm_kernel<<<dim3(M_TOT / 128, P_DIM / 128), 256, 0, stream>>>(x, wt, gate, eb, out);
  }
}

// Round 6
// 232.821 us; speedup vs baseline: 1.4133x; 1.4133x over previous
//
#include <hip/hip_runtime.h>
#include <hip/hip_bf16.h>
#include <math.h>

#define M_TOT 8192
#define D_DIM 1024
#define E_NUM 8
#define P_DIM 1024
#define K_TOT (E_NUM * D_DIM)  // 8192

typedef __attribute__((ext_vector_type(8))) short short8;
typedef __attribute__((ext_vector_type(4))) float f32x4;
typedef __attribute__((ext_vector_type(8))) unsigned short u16x8;

// round-to-nearest-even f32 -> bf16 (finite inputs)
static __device__ __forceinline__ unsigned short f2bf(float f) {
  unsigned u = __builtin_bit_cast(unsigned, f);
  unsigned r = (u + 0x7fffu + ((u >> 16) & 1u)) >> 16;
  return (unsigned short)r;
}

// ---------------- gate: softmax(x @ gate_w + gate_b) -> [M, E] fp32 ----------------
__global__ __launch_bounds__(256) void gate_kernel(const float* __restrict__ x,
                                                   const float* __restrict__ gw,
                                                   const float* __restrict__ gb,
                                                   float* __restrict__ gate) {
  const int row  = blockIdx.x * 4 + (threadIdx.x >> 6);
  const int lane = threadIdx.x & 63;
  const float* xr = x + (size_t)row * D_DIM;
  float acc[E_NUM];
#pragma unroll
  for (int e = 0; e < E_NUM; ++e) acc[e] = 0.f;
#pragma unroll
  for (int it = 0; it < 16; ++it) {
    const int d = it * 64 + lane;
    const float xv = xr[d];
    const float4* g4 = reinterpret_cast<const float4*>(gw + (size_t)d * E_NUM);
    float4 a = g4[0], b = g4[1];
    acc[0] += xv * a.x; acc[1] += xv * a.y; acc[2] += xv * a.z; acc[3] += xv * a.w;
    acc[4] += xv * b.x; acc[5] += xv * b.y; acc[6] += xv * b.z; acc[7] += xv * b.w;
  }
#pragma unroll
  for (int off = 32; off >= 1; off >>= 1) {
#pragma unroll
    for (int e = 0; e < E_NUM; ++e) acc[e] += __shfl_xor(acc[e], off, 64);
  }
  if (lane == 0) {
    float v[E_NUM], mx = -1e30f;
#pragma unroll
    for (int e = 0; e < E_NUM; ++e) { v[e] = acc[e] + gb[e]; mx = fmaxf(mx, v[e]); }
    float s = 0.f;
#pragma unroll
    for (int e = 0; e < E_NUM; ++e) { v[e] = expf(v[e] - mx); s += v[e]; }
    const float inv = 1.f / s;
#pragma unroll
    for (int e = 0; e < E_NUM; ++e) gate[(size_t)row * E_NUM + e] = v[e] * inv;
  }
}

// ---------------- W [E][D][P] f32 -> wt [P][E*D] bf16, swizzle baked per 64-short K-block ----------------
__global__ __launch_bounds__(256) void wtrans2_kernel(const float* __restrict__ w,
                                                      unsigned short* __restrict__ wt) {
  __shared__ float tile[64][65];
  const int e  = blockIdx.z;
  const int p0 = blockIdx.y * 64;
  const int d0 = blockIdx.x * 64;
  const int tx = threadIdx.x & 63;
  const int ty = threadIdx.x >> 6;
  const float* src = w + ((size_t)e * D_DIM + d0) * P_DIM + p0;
#pragma unroll
  for (int i = 0; i < 16; ++i) {
    const int dr = i * 4 + ty;
    tile[dr][tx] = src[(size_t)dr * P_DIM + tx];
  }
  __syncthreads();
#pragma unroll
  for (int i = 0; i < 16; ++i) {
    const int pr = i * 4 + ty;
    const int c = tx ^ ((pr & 7) << 3);  // involution, 16B-chunk granular
    wt[(size_t)(p0 + pr) * K_TOT + e * D_DIM + d0 + c] = f2bf(tile[tx][pr]);
  }
}

// ---------------- A'[m][e*1024+d] = bf16(gate[m,e]*x[m,d]), swizzle baked per 64-short block ----------------
__global__ __launch_bounds__(256) void aprep_kernel(const float* __restrict__ x,
                                                    const float* __restrict__ gate,
                                                    unsigned short* __restrict__ ap) {
  const int tid = threadIdx.x;
  const int m   = blockIdx.x * 2 + (tid >> 7);
  const int jd  = tid & 127;
  const float4* xp = reinterpret_cast<const float4*>(x + (size_t)m * D_DIM + jd * 8);
  const float4 p = xp[0], q = xp[1];
  unsigned short* row = ap + (size_t)m * K_TOT;
  const int cbase = (jd >> 3) * 8 + ((jd & 7) ^ (m & 7));
#pragma unroll
  for (int e = 0; e < E_NUM; ++e) {
    const float gs = gate[(size_t)m * E_NUM + e];
    u16x8 v;
    v[0] = f2bf(p.x * gs); v[1] = f2bf(p.y * gs);
    v[2] = f2bf(p.z * gs); v[3] = f2bf(p.w * gs);
    v[4] = f2bf(q.x * gs); v[5] = f2bf(q.y * gs);
    v[6] = f2bf(q.z * gs); v[7] = f2bf(q.w * gs);
    *reinterpret_cast<u16x8*>(&row[(size_t)(e * 128 + cbase) * 8]) = v;
  }
}

// ---------------- split-K 8-phase 256x256 GEMM, BK=64, 8 waves, counted vmcnt ----------------
static __device__ __forceinline__ short8 ldfrag(const unsigned short* buf, int row, int e0) {
  return *reinterpret_cast<const short8*>(&buf[row * 64 + (e0 ^ ((row & 7) << 3))]);
}

__global__ __launch_bounds__(512, 1) void gemm_sk_kernel(
    const unsigned short* __restrict__ ap,
    const unsigned short* __restrict__ wt,
    const float* __restrict__ gate,
    const float* __restrict__ eb,
    float* __restrict__ out) {
  // [buf][rowhalf][128*64]
  __shared__ __align__(16) unsigned short lA[2 * 2 * 8192];  // 64 KB
  __shared__ __align__(16) unsigned short lB[2 * 2 * 8192];  // 64 KB
  __shared__ float lG[256 * 8];                              // 8 KB  -> 136 KB

  const int tid  = threadIdx.x;
  const int lane = tid & 63;
  const int wid  = tid >> 6;
  const int wm   = wid >> 2;   // 0..1  (row half of tile)
  const int wn   = wid & 3;    // 0..3
  const int l15  = lane & 15;
  const int e0b  = (lane >> 4) * 8;

  // 256 blocks = 8 XCD groups x (kh2 x nt4 x mtl4); XCD owns 4 m-tiles exclusively.
  const int bid = blockIdx.x;
  const int c   = bid & 7, j = bid >> 3;
  const int kh  = j & 1;
  const int nt  = (j >> 1) & 3;
  const int mt  = c * 4 + (j >> 3);
  const int m0  = mt * 256, n0 = nt * 256;
  const int kb  = kh * 64;      // K-tile base (64 tiles per half)

  // gate tile [256][8]
  reinterpret_cast<float4*>(lG)[tid] =
      reinterpret_cast<const float4*>(gate + (size_t)m0 * E_NUM)[tid];
  __syncthreads();

  // staging: half-chunk = 128 rows x 64 shorts = 16KB = 2 x 512 threads x 16B
  auto stA = [&](int tt, int h) {
    const int w = kb + (tt & 63), b = tt & 1;
#pragma unroll
    for (int l = 0; l < 2; ++l) {
      const int u = tid + l * 512;
      const unsigned short* src =
          ap + (size_t)(m0 + h * 128 + (u >> 3)) * K_TOT + w * 64 + (u & 7) * 8;
      __builtin_amdgcn_global_load_lds(
          (const __attribute__((address_space(1))) void*)src,
          (__attribute__((address_space(3))) void*)&lA[(b * 2 + h) * 8192 + u * 8], 16, 0, 0);
    }
  };
  auto stB = [&](int tt, int h) {
    const int w = kb + (tt & 63), b = tt & 1;
#pragma unroll
    for (int l = 0; l < 2; ++l) {
      const int u = tid + l * 512;
      const unsigned short* src =
          wt + (size_t)(n0 + h * 128 + (u >> 3)) * K_TOT + w * 64 + (u & 7) * 8;
      __builtin_amdgcn_global_load_lds(
          (const __attribute__((address_space(1))) void*)src,
          (__attribute__((address_space(3))) void*)&lB[(b * 2 + h) * 8192 + u * 8], 16, 0, 0);
    }
  };

  f32x4 acc[8][4];
#pragma unroll
  for (int i = 0; i < 8; ++i)
#pragma unroll
    for (int jj = 0; jj < 4; ++jj)
#pragma unroll
      for (int k = 0; k < 4; ++k) acc[i][jj][k] = 0.f;

  // prologue: halves 0..5 = [B0,B1,A0,A1](t0) + [B0,B1](t1); retire tile0 (8 loads)
  stB(0, 0); stB(0, 1); stA(0, 0); stA(0, 1);
  stB(1, 0); stB(1, 1);
  asm volatile("s_waitcnt vmcnt(4)" ::: "memory");
  __builtin_amdgcn_s_barrier();
  asm volatile("" ::: "memory");

  const int rbB = (wn & 1) * 64;  // B row base within the wave's column half-chunk
  const int hB  = wn >> 1;        // B half-chunk

#pragma unroll 2
  for (int t = 0; t < 64; ++t) {
    const int b = t & 1;
    const unsigned short* bufA = lA + (b * 2 + wm) * 8192;
    const unsigned short* bufB = lB + (b * 2 + hB) * 8192;

    short8 a0[4][2], a1[4][2], b0[2][2], b1[2][2];

    // ---- phase 0: quadrant (mh0, nh0); stage AH0(t+1) ----
#pragma unroll
    for (int mi = 0; mi < 4; ++mi)
#pragma unroll
      for (int kk = 0; kk < 2; ++kk)
        a0[mi][kk] = ldfrag(bufA, mi * 16 + l15, kk * 32 + e0b);
#pragma unroll
    for (int ni = 0; ni < 2; ++ni)
#pragma unroll
      for (int kk = 0; kk < 2; ++kk)
        b0[ni][kk] = ldfrag(bufB, rbB + ni * 16 + l15, kk * 32 + e0b);
    stA(t + 1, 0);
    __builtin_amdgcn_s_barrier();
    asm volatile("s_waitcnt lgkmcnt(0)" ::: "memory");
    __builtin_amdgcn_s_setprio(1);
#pragma unroll
    for (int mi = 0; mi < 4; ++mi)
#pragma unroll
      for (int ni = 0; ni < 2; ++ni)
#pragma unroll
        for (int kk = 0; kk < 2; ++kk)
          acc[mi][ni] = __builtin_amdgcn_mfma_f32_16x16x32_bf16(a0[mi][kk], b0[ni][kk], acc[mi][ni], 0, 0, 0);
    __builtin_amdgcn_s_setprio(0);
    __builtin_amdgcn_s_barrier();
    asm volatile("" ::: "memory");

    // ---- phase 1: quadrant (mh0, nh1); stage AH1(t+1) ----
#pragma unroll
    for (int ni = 0; ni < 2; ++ni)
#pragma unroll
      for (int kk = 0; kk < 2; ++kk)
        b1[ni][kk] = ldfrag(bufB, rbB + 32 + ni * 16 + l15, kk * 32 + e0b);
    stA(t + 1, 1);
    __builtin_amdgcn_s_barrier();
    asm volatile("s_waitcnt lgkmcnt(0)" ::: "memory");
    __builtin_amdgcn_s_setprio(1);
#pragma unroll
    for (int mi = 0; mi < 4; ++mi)
#pragma unroll
      for (int ni = 0; ni < 2; ++ni)
#pragma unroll
        for (int kk = 0; kk < 2; ++kk)
          acc[mi][2 + ni] = __builtin_amdgcn_mfma_f32_16x16x32_bf16(a0[mi][kk], b1[ni][kk], acc[mi][2 + ni], 0, 0, 0);
    __builtin_amdgcn_s_setprio(0);
    __builtin_amdgcn_s_barrier();
    asm volatile("" ::: "memory");

    // ---- phase 2: quadrant (mh1, nh0); stage BH0(t+2) (cur-buf B dead since ph1) ----
#pragma unroll
    for (int mi = 0; mi < 4; ++mi)
#pragma unroll
      for (int kk = 0; kk < 2; ++kk)
        a1[mi][kk] = ldfrag(bufA, 64 + mi * 16 + l15, kk * 32 + e0b);
    stB(t + 2, 0);
    __builtin_amdgcn_s_barrier();
    asm volatile("s_waitcnt lgkmcnt(0)" ::: "memory");
    __builtin_amdgcn_s_setprio(1);
#pragma unroll
    for (int mi = 0; mi < 4; ++mi)
#pragma unroll
      for (int ni = 0; ni < 2; ++ni)
#pragma unroll
        for (int kk = 0; kk < 2; ++kk)
          acc[4 + mi][ni] = __builtin_amdgcn_mfma_f32_16x16x32_bf16(a1[mi][kk], b0[ni][kk], acc[4 + mi][ni], 0, 0, 0);
    __builtin_amdgcn_s_setprio(0);
    __builtin_amdgcn_s_barrier();
    asm volatile("" ::: "memory");

    // ---- phase 3: quadrant (mh1, nh1); stage BH1(t+2); end-of-tile counted wait ----
    stB(t + 2, 1);
    __builtin_amdgcn_s_setprio(1);
#pragma unroll
    for (int mi = 0; mi < 4; ++mi)
#pragma unroll
      for (int ni = 0; ni < 2; ++ni)
#pragma unroll
        for (int kk = 0; kk < 2; ++kk)
          acc[4 + mi][2 + ni] = __builtin_amdgcn_mfma_f32_16x16x32_bf16(a1[mi][kk], b1[ni][kk], acc[4 + mi][2 + ni], 0, 0, 0);
    __builtin_amdgcn_s_setprio(0);
    asm volatile("s_waitcnt vmcnt(4)" ::: "memory");  // tile t+1 fully resident; 2 halves in flight
    __builtin_amdgcn_s_barrier();
    asm volatile("" ::: "memory");
  }

  // ---- epilogue: atomic accumulate (+ gate-weighted bias on kh==0) ----
#pragma unroll
  for (int nf = 0; nf < 4; ++nf) {
    const int C = n0 + wn * 64 + nf * 16 + l15;
    float lb[E_NUM];
    if (kh == 0) {
#pragma unroll
      for (int e = 0; e < E_NUM; ++e) lb[e] = eb[(size_t)e * P_DIM + C];
    }
#pragma unroll
    for (int mf = 0; mf < 8; ++mf) {
#pragma unroll
      for (int reg = 0; reg < 4; ++reg) {
        const int rl = wm * 128 + mf * 16 + (lane >> 4) * 4 + reg;
        float v = acc[mf][nf][reg];
        if (kh == 0) {
          float bs = 0.f;
#pragma unroll
          for (int e = 0; e < E_NUM; ++e) bs += lG[rl * 8 + e] * lb[e];
          v += bs;
        }
        atomicAdd(&out[(size_t)(m0 + rl) * P_DIM + C], v);
      }
    }
  }
}

// ============================ FALLBACK PATH (round-2, passing) ============================

__global__ __launch_bounds__(256) void wtrans_kernel(const float* __restrict__ w,
                                                     unsigned short* __restrict__ wt) {
  __shared__ float tile[64][65];
  const int e  = blockIdx.z;
  const int p0 = blockIdx.y * 64;
  const int d0 = blockIdx.x * 64;
  const int tx = threadIdx.x & 63;
  const int ty = threadIdx.x >> 6;
  const float* src = w + ((size_t)e * D_DIM + d0) * P_DIM + p0;
#pragma unroll
  for (int i = 0; i < 16; ++i) {
    const int dr = i * 4 + ty;
    tile[dr][tx] = src[(size_t)dr * P_DIM + tx];
  }
  __syncthreads();
  unsigned short* dst = wt + ((size_t)e * P_DIM + p0) * D_DIM + d0;
#pragma unroll
  for (int i = 0; i < 16; ++i) {
    const int pr = i * 4 + ty;
    const int cc = tx ^ ((pr & 7) << 3);
    dst[(size_t)pr * D_DIM + cc] = f2bf(tile[tx][pr]);
  }
}

__global__ __launch_bounds__(256, 2) void moe_gemm_kernel(
    const float* __restrict__ x,
    const unsigned short* __restrict__ wt,
    const float* __restrict__ gate,
    const float* __restrict__ eb,
    float* __restrict__ out) {
  __shared__ unsigned short lA[128 * 64];
  __shared__ unsigned short lB[128 * 64];
  __shared__ float lG[128 * 8];
  __shared__ float lBias[E_NUM * 128];

  const int tid  = threadIdx.x;
  const int lane = tid & 63;
  const int wid  = tid >> 6;
  const int wr   = wid >> 1, wc = wid & 1;
  const int m0   = blockIdx.x * 128;
  const int n0   = blockIdx.y * 128;

  reinterpret_cast<float4*>(lG)[tid] =
      reinterpret_cast<const float4*>(gate + (size_t)m0 * E_NUM)[tid];
  {
    const int e = tid >> 5, cc = (tid & 31) * 4;
    *reinterpret_cast<float4*>(&lBias[e * 128 + cc]) =
        *reinterpret_cast<const float4*>(&eb[(size_t)e * P_DIM + n0 + cc]);
  }
  __syncthreads();

  const int rA   = tid >> 1;
  const int colA = (tid & 1) * 32;
  const float* xrow = x + (size_t)(m0 + rA) * D_DIM + colA;

  f32x4 acc[4][4];
#pragma unroll
  for (int i = 0; i < 4; ++i)
#pragma unroll
    for (int jj = 0; jj < 4; ++jj)
#pragma unroll
      for (int k = 0; k < 4; ++k) acc[i][jj][k] = 0.f;

  for (int e = 0; e < E_NUM; ++e) {
    const float gs = lG[rA * 8 + e];
    const unsigned short* wte = wt + ((size_t)e * P_DIM + n0) * D_DIM;
    for (int kt = 0; kt < 16; ++kt) {
      __syncthreads();
      const float4* apv = reinterpret_cast<const float4*>(xrow + kt * 64);
#pragma unroll
      for (int jj = 0; jj < 4; ++jj) {
        float4 p = apv[2 * jj], q = apv[2 * jj + 1];
        u16x8 v;
        v[0] = f2bf(p.x * gs); v[1] = f2bf(p.y * gs);
        v[2] = f2bf(p.z * gs); v[3] = f2bf(p.w * gs);
        v[4] = f2bf(q.x * gs); v[5] = f2bf(q.y * gs);
        v[6] = f2bf(q.z * gs); v[7] = f2bf(q.w * gs);
        const int idx = rA * 64 + ((colA + jj * 8) ^ ((rA & 7) << 3));
        *reinterpret_cast<u16x8*>(&lA[idx]) = v;
      }
#pragma unroll
      for (int i = 0; i < 4; ++i) {
        const int u  = tid + i * 256;
        const int rr = u >> 3;
        const int cc = u & 7;
        const unsigned short* src = wte + (size_t)rr * D_DIM + kt * 64 + cc * 8;
        __builtin_amdgcn_global_load_lds(
            (const __attribute__((address_space(1))) void*)src,
            (__attribute__((address_space(3))) void*)&lB[u * 8], 16, 0, 0);
      }
      __syncthreads();
#pragma unroll
      for (int kk = 0; kk < 2; ++kk) {
        const int e0 = kk * 32 + (lane >> 4) * 8;
        short8 a[4], b[4];
#pragma unroll
        for (int m = 0; m < 4; ++m) {
          const int r = wr * 64 + m * 16 + (lane & 15);
          a[m] = *reinterpret_cast<const short8*>(&lA[r * 64 + (e0 ^ ((r & 7) << 3))]);
        }
#pragma unroll
        for (int n = 0; n < 4; ++n) {
          const int r = wc * 64 + n * 16 + (lane & 15);
          b[n] = *reinterpret_cast<const short8*>(&lB[r * 64 + (e0 ^ ((r & 7) << 3))]);
        }
#pragma unroll
        for (int m = 0; m < 4; ++m)
#pragma unroll
          for (int n = 0; n < 4; ++n)
            acc[m][n] = __builtin_amdgcn_mfma_f32_16x16x32_bf16(a[m], b[n], acc[m][n], 0, 0, 0);
      }
    }
  }

#pragma unroll
  for (int m = 0; m < 4; ++m) {
#pragma unroll
    for (int n = 0; n < 4; ++n) {
      const int rbase = wr * 64 + m * 16 + ((lane >> 4) * 4);
      const int cl    = wc * 64 + n * 16 + (lane & 15);
#pragma unroll
      for (int reg = 0; reg < 4; ++reg) {
        const int r = rbase + reg;
        float bsum = 0.f;
#pragma unroll
        for (int e = 0; e < E_NUM; ++e) bsum += lG[r * 8 + e] * lBias[e * 128 + cl];
        out[(size_t)(m0 + r) * P_DIM + n0 + cl] = acc[m][n][reg] + bsum;
      }
    }
  }
}

// ============================ launch ============================

extern "C" void kernel_launch(void* const* d_in, const int* in_sizes, int n_in,
                              void* d_out, int out_size, void* d_ws, size_t ws_size,
                              hipStream_t stream) {
  const float* x  = (const float*)d_in[0];
  const float* gw = (const float*)d_in[1];
  const float* gb = (const float*)d_in[2];
  const float* ew = (const float*)d_in[3];
  const float* eb = (const float*)d_in[4];
  float* out = (float*)d_out;

  char* ws = (char*)d_ws;
  float* gate        = (float*)ws;                     // 256 KiB
  unsigned short* wt = (unsigned short*)(ws + 262144); // 16 MiB

  const size_t need_big = 262144ull + 16777216ull + 134217728ull;

  gate_kernel<<<M_TOT / 4, 256, 0, stream>>>(x, gw, gb, gate);

  if (ws_size >= need_big) {
    unsigned short* apb = (unsigned short*)(ws + 262144 + 16777216);  // 128 MiB
    hipMemsetAsync(d_out, 0, (size_t)out_size * sizeof(float), stream);
    wtrans2_kernel<<<dim3(D_DIM / 64, P_DIM / 64, E_NUM), 256, 0, stream>>>(ew, wt);
    aprep_kernel<<<M_TOT / 2, 256, 0, stream>>>(x, gate, apb);
    gemm_sk_kernel<<<256, 512, 0, stream>>>(apb, wt, gate, eb, out);
  } else {
    wtrans_kernel<<<dim3(D_DIM / 64, P_DIM / 64, E_NUM), 256, 0, stream>>>(ew, wt);
    moe_gemm_kernel<<<dim3(M_TOT / 128, P_DIM / 128), 256, 0, stream>>>(x, wt, gate, eb, out);
  }
}